// Round 1
// baseline (174.073 us; speedup 1.0000x reference)
//
#include <hip/hip_runtime.h>
#include <math.h>

namespace {
constexpr int kN = 16, kC = 64, kH = 224, kW = 224;
constexpr int kOH = kH / 2, kOW = kW / 2;          // 112 x 112
constexpr int R_OUT = 8;                           // output rows per block
constexpr int BAND_ROWS = 2 * R_OUT + 6;           // 22 lo/hi rows (halo 3 each side)
constexpr int NBANDS = kOH / R_OUT;                // 14
constexpr float kMagBias = 0.01f;
constexpr float kMB2 = kMagBias * kMagBias;
constexpr float kSqrtHalf = 0.70710678118654752f;
}  // namespace

__device__ __forceinline__ float magf(float re, float im) {
    return sqrtf(fmaf(re, re, fmaf(im, im, kMB2))) - kMagBias;
}

__global__ __launch_bounds__(256, 4)
void scat_fused_kernel(const float* __restrict__ x, float* __restrict__ out) {
    // Interleaved horizontal filter outputs: {lo, hi} per (row, col).
    __shared__ float2 sLH[BAND_ROWS][kW];          // 22*224*8 = 39,424 B

    const int b    = blockIdx.x;
    const int band = b % NBANDS;
    const int ch   = b / NBANDS;                   // n*kC + c
    const int i0   = band * R_OUT;                 // first output row of band
    const int rbase = 2 * i0 - 3;                  // first lo/hi image row (may be <0)
    const int tid  = threadIdx.x;

    const float h0[5] = {-0.05f, 0.25f, 0.6f, 0.25f, -0.05f};
    const float h1[7] = {-0.0107142857142857f, 0.0535714285714286f,
                          0.2607142857142857f, -0.6071428571428571f,
                          0.2607142857142857f, 0.0535714285714286f,
                         -0.0107142857142857f};

    const float* __restrict__ xp = x + (size_t)ch * (kH * kW);

    // ---------------- Phase 1: horizontal lo/hi -> LDS ----------------
    // Tasks: 22 rows x 56 col-groups (4 cols each).
    for (int task = tid; task < BAND_ROWS * 56; task += 256) {
        const int s  = task / 56;
        const int cg = task - s * 56;
        int r = rbase + s;
        r = (r < 0) ? (-1 - r) : ((r > kH - 1) ? (2 * kH - 1 - r) : r);
        const float* __restrict__ rowp = xp + r * kW;
        const int c0 = cg * 4;

        float xv[10];  // input cols c0-3 .. c0+6
        if (cg >= 1 && cg <= 54) {
            const float4 A  = *reinterpret_cast<const float4*>(rowp + c0 - 4);
            const float4 B  = *reinterpret_cast<const float4*>(rowp + c0);
            const float4 Cv = *reinterpret_cast<const float4*>(rowp + c0 + 4);
            xv[0] = A.y;  xv[1] = A.z;  xv[2] = A.w;
            xv[3] = B.x;  xv[4] = B.y;  xv[5] = B.z;  xv[6] = B.w;
            xv[7] = Cv.x; xv[8] = Cv.y; xv[9] = Cv.z;
        } else {
            #pragma unroll
            for (int k = 0; k < 10; ++k) {
                int cc = c0 - 3 + k;
                cc = (cc < 0) ? (-1 - cc) : ((cc > kW - 1) ? (2 * kW - 1 - cc) : cc);
                xv[k] = rowp[cc];
            }
        }

        float lo[4], hi[4];
        #pragma unroll
        for (int u = 0; u < 4; ++u) {
            lo[u] = h0[0] * xv[u + 1] + h0[1] * xv[u + 2] + h0[2] * xv[u + 3]
                  + h0[3] * xv[u + 4] + h0[4] * xv[u + 5];
            hi[u] = h1[0] * xv[u + 0] + h1[1] * xv[u + 1] + h1[2] * xv[u + 2]
                  + h1[3] * xv[u + 3] + h1[4] * xv[u + 4] + h1[5] * xv[u + 5]
                  + h1[6] * xv[u + 6];
        }
        float4* dst = reinterpret_cast<float4*>(&sLH[s][c0]);
        dst[0] = make_float4(lo[0], hi[0], lo[1], hi[1]);
        dst[1] = make_float4(lo[2], hi[2], lo[3], hi[3]);
    }
    __syncthreads();

    // ---------------- Phase 2: vertical filters + q2c + mag + pool ----------------
    const int n = ch / kC;
    const int c = ch - n * kC;
    const size_t plane   = (size_t)kOH * kOW;      // 12544
    const size_t ostride = (size_t)kC * plane;     // orientation stride in output
    float* __restrict__ outp = out + ((size_t)n * 7 * kC + c) * plane;

    for (int task = tid; task < R_OUT * kOW; task += 256) {
        const int ii = task / kOW;                 // 0..R_OUT-1
        const int j  = task - ii * kOW;            // 0..111
        const int s1 = 2 * ii + 3;                 // LDS row of image row 2*(i0+ii)

        float lo0[8], hi0[8], lo1[8], hi1[8];      // window rows s1-3 .. s1+4, cols 2j,2j+1
        #pragma unroll
        for (int k = 0; k < 8; ++k) {
            const float4 v = *reinterpret_cast<const float4*>(&sLH[s1 - 3 + k][2 * j]);
            lo0[k] = v.x; hi0[k] = v.y; lo1[k] = v.z; hi1[k] = v.w;
        }

        // 7-tap vertical (lh from lo, hh from hi). top row uses k=0..6, bottom k=1..7.
        float lh_a = 0.f, lh_b = 0.f, lh_c = 0.f, lh_d = 0.f;
        float hh_a = 0.f, hh_b = 0.f, hh_c = 0.f, hh_d = 0.f;
        #pragma unroll
        for (int t = 0; t < 7; ++t) {
            lh_a = fmaf(h1[t], lo0[t],     lh_a);
            lh_b = fmaf(h1[t], lo1[t],     lh_b);
            lh_c = fmaf(h1[t], lo0[t + 1], lh_c);
            lh_d = fmaf(h1[t], lo1[t + 1], lh_d);
            hh_a = fmaf(h1[t], hi0[t],     hh_a);
            hh_b = fmaf(h1[t], hi1[t],     hh_b);
            hh_c = fmaf(h1[t], hi0[t + 1], hh_c);
            hh_d = fmaf(h1[t], hi1[t + 1], hh_d);
        }
        // 5-tap vertical (ll from lo, hl from hi). top uses k=1..5, bottom k=2..6.
        float ll_a = 0.f, ll_b = 0.f, ll_c = 0.f, ll_d = 0.f;
        float hl_a = 0.f, hl_b = 0.f, hl_c = 0.f, hl_d = 0.f;
        #pragma unroll
        for (int t = 0; t < 5; ++t) {
            ll_a = fmaf(h0[t], lo0[t + 1], ll_a);
            ll_b = fmaf(h0[t], lo1[t + 1], ll_b);
            ll_c = fmaf(h0[t], lo0[t + 2], ll_c);
            ll_d = fmaf(h0[t], lo1[t + 2], ll_d);
            hl_a = fmaf(h0[t], hi0[t + 1], hl_a);
            hl_b = fmaf(h0[t], hi1[t + 1], hl_b);
            hl_c = fmaf(h0[t], hi0[t + 2], hl_c);
            hl_d = fmaf(h0[t], hi1[t + 2], hl_d);
        }

        const float llp = fmaxf(fmaxf(ll_a, ll_b), fmaxf(ll_c, ll_d));

        // q2c: a=even/even, b=even/odd, c=odd/even, d=odd/odd
        const float m15  = magf((lh_a - lh_d) * kSqrtHalf, (lh_b + lh_c) * kSqrtHalf);
        const float m165 = magf((lh_a + lh_d) * kSqrtHalf, (lh_b - lh_c) * kSqrtHalf);
        const float m45  = magf((hh_a - hh_d) * kSqrtHalf, (hh_b + hh_c) * kSqrtHalf);
        const float m135 = magf((hh_a + hh_d) * kSqrtHalf, (hh_b - hh_c) * kSqrtHalf);
        const float m75  = magf((hl_a - hl_d) * kSqrtHalf, (hl_b + hl_c) * kSqrtHalf);
        const float m105 = magf((hl_a + hl_d) * kSqrtHalf, (hl_b - hl_c) * kSqrtHalf);

        const size_t pix = (size_t)(i0 + ii) * kOW + j;
        outp[pix]               = llp;   // o=0 (pooled LL)
        outp[ostride     + pix] = m15;   // o=1
        outp[2 * ostride + pix] = m45;   // o=2
        outp[3 * ostride + pix] = m75;   // o=3
        outp[4 * ostride + pix] = m105;  // o=4
        outp[5 * ostride + pix] = m135;  // o=5
        outp[6 * ostride + pix] = m165;  // o=6
    }
}

extern "C" void kernel_launch(void* const* d_in, const int* in_sizes, int n_in,
                              void* d_out, int out_size, void* d_ws, size_t ws_size,
                              hipStream_t stream) {
    const float* x = (const float*)d_in[0];
    float* out = (float*)d_out;
    const int grid = kN * kC * NBANDS;  // 16*64*14 = 14336
    scat_fused_kernel<<<grid, 256, 0, stream>>>(x, out);
}

// Round 2
// 143.625 us; speedup vs baseline: 1.2120x; 1.2120x over previous
//
#include <hip/hip_runtime.h>
#include <hip/hip_fp16.h>
#include <math.h>

namespace {
constexpr int kN = 16, kC = 64, kH = 224, kW = 224;
constexpr int kOH = kH / 2, kOW = kW / 2;          // 112 x 112
constexpr int R_OUT = 8;                           // output rows per block
constexpr int BAND_ROWS = 2 * R_OUT + 6;           // 22 lo/hi rows (halo 3 each side)
constexpr int NBANDS = kOH / R_OUT;                // 14
constexpr int PADW = kW + 4;                       // pad to shift banks across rows
constexpr float kMagBias = 0.01f;
constexpr float kMB2 = kMagBias * kMagBias;
constexpr float kSqrtHalf = 0.70710678118654752f;
}  // namespace

__device__ __forceinline__ float magf(float re, float im) {
    return __builtin_amdgcn_sqrtf(fmaf(re, re, fmaf(im, im, kMB2))) - kMagBias;
}

__global__ __launch_bounds__(256, 8)
void scat_fused_kernel(const float* __restrict__ x, float* __restrict__ out) {
    // Packed horizontal filter outputs: per (row, col) a __half2 {lo, hi}.
    // Row stride PADW*4 = 912 B (not a multiple of 128) to spread banks.
    __shared__ __half2 sLH[BAND_ROWS][PADW];       // 22*228*4 = 20,064 B -> 8 blocks/CU

    const int b    = blockIdx.x;
    const int band = b % NBANDS;
    const int ch   = b / NBANDS;                   // n*kC + c
    const int i0   = band * R_OUT;                 // first output row of band
    const int rbase = 2 * i0 - 3;                  // first lo/hi image row (may be <0)
    const int tid  = threadIdx.x;

    const float h0[5] = {-0.05f, 0.25f, 0.6f, 0.25f, -0.05f};
    const float h1[7] = {-0.0107142857142857f, 0.0535714285714286f,
                          0.2607142857142857f, -0.6071428571428571f,
                          0.2607142857142857f, 0.0535714285714286f,
                         -0.0107142857142857f};

    const float* __restrict__ xp = x + (size_t)ch * (kH * kW);

    // ---------------- Phase 1: horizontal lo/hi -> LDS (packed fp16) ----------------
    // Tasks: 22 rows x 56 col-groups (4 cols each).
    for (int task = tid; task < BAND_ROWS * 56; task += 256) {
        const int s  = task / 56;
        const int cg = task - s * 56;
        int r = rbase + s;
        r = (r < 0) ? (-1 - r) : ((r > kH - 1) ? (2 * kH - 1 - r) : r);
        const float* __restrict__ rowp = xp + r * kW;
        const int c0 = cg * 4;

        float xv[10];  // input cols c0-3 .. c0+6
        if (cg >= 1 && cg <= 54) {
            const float4 A  = *reinterpret_cast<const float4*>(rowp + c0 - 4);
            const float4 B  = *reinterpret_cast<const float4*>(rowp + c0);
            const float4 Cv = *reinterpret_cast<const float4*>(rowp + c0 + 4);
            xv[0] = A.y;  xv[1] = A.z;  xv[2] = A.w;
            xv[3] = B.x;  xv[4] = B.y;  xv[5] = B.z;  xv[6] = B.w;
            xv[7] = Cv.x; xv[8] = Cv.y; xv[9] = Cv.z;
        } else {
            #pragma unroll
            for (int k = 0; k < 10; ++k) {
                int cc = c0 - 3 + k;
                cc = (cc < 0) ? (-1 - cc) : ((cc > kW - 1) ? (2 * kW - 1 - cc) : cc);
                xv[k] = rowp[cc];
            }
        }

        unsigned int pk[4];
        #pragma unroll
        for (int u = 0; u < 4; ++u) {
            const float lo = h0[0] * xv[u + 1] + h0[1] * xv[u + 2] + h0[2] * xv[u + 3]
                           + h0[3] * xv[u + 4] + h0[4] * xv[u + 5];
            const float hi = h1[0] * xv[u + 0] + h1[1] * xv[u + 1] + h1[2] * xv[u + 2]
                           + h1[3] * xv[u + 3] + h1[4] * xv[u + 4] + h1[5] * xv[u + 5]
                           + h1[6] * xv[u + 6];
            __half2 p = __floats2half2_rn(lo, hi);
            pk[u] = *reinterpret_cast<unsigned int*>(&p);
        }
        *reinterpret_cast<uint4*>(&sLH[s][c0]) =
            make_uint4(pk[0], pk[1], pk[2], pk[3]);
    }
    __syncthreads();

    // ---------------- Phase 2: vertical filters + q2c + mag + pool ----------------
    const int n = ch / kC;
    const int c = ch - n * kC;
    const size_t plane   = (size_t)kOH * kOW;      // 12544
    const size_t ostride = (size_t)kC * plane;     // orientation stride in output
    float* __restrict__ outp = out + ((size_t)n * 7 * kC + c) * plane;

    for (int task = tid; task < R_OUT * kOW; task += 256) {
        const int ii = task / kOW;                 // 0..R_OUT-1
        const int j  = task - ii * kOW;            // 0..111
        const int s1 = 2 * ii + 3;                 // LDS row of image row 2*(i0+ii)

        // Row-streaming accumulation over the 8 window rows (s1-3 .. s1+4).
        // Keeps ~30 VGPRs live instead of ~60.
        float lh_a = 0.f, lh_b = 0.f, lh_c = 0.f, lh_d = 0.f;
        float hh_a = 0.f, hh_b = 0.f, hh_c = 0.f, hh_d = 0.f;
        float ll_a = 0.f, ll_b = 0.f, ll_c = 0.f, ll_d = 0.f;
        float hl_a = 0.f, hl_b = 0.f, hl_c = 0.f, hl_d = 0.f;

        #pragma unroll
        for (int k = 0; k < 8; ++k) {
            const __half2 pa = sLH[s1 - 3 + k][2 * j];       // {lo0, hi0}
            const __half2 pb = sLH[s1 - 3 + k][2 * j + 1];   // {lo1, hi1}
            const float lo0 = __low2float(pa), hi0 = __high2float(pa);
            const float lo1 = __low2float(pb), hi1 = __high2float(pb);

            if (k <= 6) {                 // 7-tap, even output row (taps h1[k])
                lh_a = fmaf(h1[k], lo0, lh_a);
                lh_b = fmaf(h1[k], lo1, lh_b);
                hh_a = fmaf(h1[k], hi0, hh_a);
                hh_b = fmaf(h1[k], hi1, hh_b);
            }
            if (k >= 1) {                 // 7-tap, odd output row (taps h1[k-1])
                lh_c = fmaf(h1[k - 1], lo0, lh_c);
                lh_d = fmaf(h1[k - 1], lo1, lh_d);
                hh_c = fmaf(h1[k - 1], hi0, hh_c);
                hh_d = fmaf(h1[k - 1], hi1, hh_d);
            }
            if (k >= 1 && k <= 5) {       // 5-tap, even output row (taps h0[k-1])
                ll_a = fmaf(h0[k - 1], lo0, ll_a);
                ll_b = fmaf(h0[k - 1], lo1, ll_b);
                hl_a = fmaf(h0[k - 1], hi0, hl_a);
                hl_b = fmaf(h0[k - 1], hi1, hl_b);
            }
            if (k >= 2 && k <= 6) {       // 5-tap, odd output row (taps h0[k-2])
                ll_c = fmaf(h0[k - 2], lo0, ll_c);
                ll_d = fmaf(h0[k - 2], lo1, ll_d);
                hl_c = fmaf(h0[k - 2], hi0, hl_c);
                hl_d = fmaf(h0[k - 2], hi1, hl_d);
            }
        }

        const float llp = fmaxf(fmaxf(ll_a, ll_b), fmaxf(ll_c, ll_d));

        // q2c: a=even/even, b=even/odd, c=odd/even, d=odd/odd
        const float m15  = magf((lh_a - lh_d) * kSqrtHalf, (lh_b + lh_c) * kSqrtHalf);
        const float m165 = magf((lh_a + lh_d) * kSqrtHalf, (lh_b - lh_c) * kSqrtHalf);
        const float m45  = magf((hh_a - hh_d) * kSqrtHalf, (hh_b + hh_c) * kSqrtHalf);
        const float m135 = magf((hh_a + hh_d) * kSqrtHalf, (hh_b - hh_c) * kSqrtHalf);
        const float m75  = magf((hl_a - hl_d) * kSqrtHalf, (hl_b + hl_c) * kSqrtHalf);
        const float m105 = magf((hl_a + hl_d) * kSqrtHalf, (hl_b - hl_c) * kSqrtHalf);

        const size_t pix = (size_t)(i0 + ii) * kOW + j;
        outp[pix]               = llp;   // o=0 (pooled LL)
        outp[ostride     + pix] = m15;   // o=1
        outp[2 * ostride + pix] = m45;   // o=2
        outp[3 * ostride + pix] = m75;   // o=3
        outp[4 * ostride + pix] = m105;  // o=4
        outp[5 * ostride + pix] = m135;  // o=5
        outp[6 * ostride + pix] = m165;  // o=6
    }
}

extern "C" void kernel_launch(void* const* d_in, const int* in_sizes, int n_in,
                              void* d_out, int out_size, void* d_ws, size_t ws_size,
                              hipStream_t stream) {
    const float* x = (const float*)d_in[0];
    float* out = (float*)d_out;
    const int grid = kN * kC * NBANDS;  // 16*64*14 = 14336
    scat_fused_kernel<<<grid, 256, 0, stream>>>(x, out);
}

// Round 4
// 131.203 us; speedup vs baseline: 1.3267x; 1.0947x over previous
//
#include <hip/hip_runtime.h>
#include <hip/hip_fp16.h>
#include <math.h>

namespace {
constexpr int kN = 16, kC = 64, kH = 224, kW = 224;
constexpr int kOH = kH / 2, kOW = kW / 2;          // 112 x 112
constexpr int R_OUT = 8;                           // output rows per block
constexpr int BAND_ROWS = 2 * R_OUT + 6;           // 22 lo/hi rows (halo 3 each side)
constexpr int NBANDS = kOH / R_OUT;                // 14
constexpr int PADW = kW + 4;                       // pad to shift banks across rows
constexpr int kGrid = kN * kC * NBANDS;            // 14336 (multiple of 8)
constexpr int kChunk = kGrid / 8;                  // 1792 blocks per XCD
constexpr float kMagBias = 0.01f;
constexpr float kMB2 = kMagBias * kMagBias;
constexpr float kSqrtHalf = 0.70710678118654752f;
}  // namespace

typedef float v2f __attribute__((ext_vector_type(2)));

__device__ __forceinline__ float magf(float re, float im) {
    return __builtin_amdgcn_sqrtf(fmaf(re, re, fmaf(im, im, kMB2))) - kMagBias;
}

__device__ __forceinline__ void unpack2(unsigned u, float& a, float& b) {
    const __half2 h = __builtin_bit_cast(__half2, u);
    a = __low2float(h);
    b = __high2float(h);
}

__device__ __forceinline__ void nt_store2(float* p, float a, float b) {
    v2f v; v.x = a; v.y = b;
    __builtin_nontemporal_store(v, reinterpret_cast<v2f*>(p));
}

struct Acc {
    float lh_a, lh_b, lh_c, lh_d;
    float hh_a, hh_b, hh_c, hh_d;
    float ll_a, ll_b, ll_c, ll_d;
    float hl_a, hl_b, hl_c, hl_d;
};

__device__ __forceinline__ void acc_init(Acc& A) {
    A.lh_a = A.lh_b = A.lh_c = A.lh_d = 0.f;
    A.hh_a = A.hh_b = A.hh_c = A.hh_d = 0.f;
    A.ll_a = A.ll_b = A.ll_c = A.ll_d = 0.f;
    A.hl_a = A.hl_b = A.hl_c = A.hl_d = 0.f;
}

// One window-row step; k is a compile-time unroll index so the guards fold.
__device__ __forceinline__ void acc_step(Acc& A, int k, float lo0, float hi0,
                                         float lo1, float hi1,
                                         const float* __restrict__ h0,
                                         const float* __restrict__ h1) {
    if (k <= 6) {                 // 7-tap, even output row (taps h1[k])
        A.lh_a = fmaf(h1[k], lo0, A.lh_a);
        A.lh_b = fmaf(h1[k], lo1, A.lh_b);
        A.hh_a = fmaf(h1[k], hi0, A.hh_a);
        A.hh_b = fmaf(h1[k], hi1, A.hh_b);
    }
    if (k >= 1) {                 // 7-tap, odd output row (taps h1[k-1])
        A.lh_c = fmaf(h1[k - 1], lo0, A.lh_c);
        A.lh_d = fmaf(h1[k - 1], lo1, A.lh_d);
        A.hh_c = fmaf(h1[k - 1], hi0, A.hh_c);
        A.hh_d = fmaf(h1[k - 1], hi1, A.hh_d);
    }
    if (k >= 1 && k <= 5) {       // 5-tap, even output row (taps h0[k-1])
        A.ll_a = fmaf(h0[k - 1], lo0, A.ll_a);
        A.ll_b = fmaf(h0[k - 1], lo1, A.ll_b);
        A.hl_a = fmaf(h0[k - 1], hi0, A.hl_a);
        A.hl_b = fmaf(h0[k - 1], hi1, A.hl_b);
    }
    if (k >= 2 && k <= 6) {       // 5-tap, odd output row (taps h0[k-2])
        A.ll_c = fmaf(h0[k - 2], lo0, A.ll_c);
        A.ll_d = fmaf(h0[k - 2], lo1, A.ll_d);
        A.hl_c = fmaf(h0[k - 2], hi0, A.hl_c);
        A.hl_d = fmaf(h0[k - 2], hi1, A.hl_d);
    }
}

__global__ __launch_bounds__(256, 8)
void scat_fused_kernel(const float* __restrict__ x, float* __restrict__ out) {
    // Packed horizontal filter outputs: per (row, col) a __half2 {lo, hi}.
    __shared__ __half2 sLH[BAND_ROWS][PADW];       // 22*228*4 = 20,064 B -> 8 blocks/CU

    // XCD-aware swizzle: physical blocks round-robin XCDs (phys % 8); remap so
    // each XCD owns a contiguous run of 1792 logical blocks -> adjacent bands
    // of a channel share an XCD's L2 and their halo rows become L2 hits.
    const int phys = blockIdx.x;
    const int b    = (phys & 7) * kChunk + (phys >> 3);

    const int band = b % NBANDS;
    const int ch   = b / NBANDS;                   // n*kC + c
    const int i0   = band * R_OUT;                 // first output row of band
    const int rbase = 2 * i0 - 3;                  // first lo/hi image row (may be <0)
    const int tid  = threadIdx.x;

    const float h0[5] = {-0.05f, 0.25f, 0.6f, 0.25f, -0.05f};
    const float h1[7] = {-0.0107142857142857f, 0.0535714285714286f,
                          0.2607142857142857f, -0.6071428571428571f,
                          0.2607142857142857f, 0.0535714285714286f,
                         -0.0107142857142857f};

    const float* __restrict__ xp = x + (size_t)ch * (kH * kW);

    // ---------------- Phase 1: horizontal lo/hi -> LDS (packed fp16) ----------------
    for (int task = tid; task < BAND_ROWS * 56; task += 256) {
        const int s  = task / 56;
        const int cg = task - s * 56;
        int r = rbase + s;
        r = (r < 0) ? (-1 - r) : ((r > kH - 1) ? (2 * kH - 1 - r) : r);
        const float* __restrict__ rowp = xp + r * kW;
        const int c0 = cg * 4;

        float xv[10];  // input cols c0-3 .. c0+6
        if (cg >= 1 && cg <= 54) {
            const float4 A  = *reinterpret_cast<const float4*>(rowp + c0 - 4);
            const float4 B  = *reinterpret_cast<const float4*>(rowp + c0);
            const float4 Cv = *reinterpret_cast<const float4*>(rowp + c0 + 4);
            xv[0] = A.y;  xv[1] = A.z;  xv[2] = A.w;
            xv[3] = B.x;  xv[4] = B.y;  xv[5] = B.z;  xv[6] = B.w;
            xv[7] = Cv.x; xv[8] = Cv.y; xv[9] = Cv.z;
        } else {
            #pragma unroll
            for (int k = 0; k < 10; ++k) {
                int cc = c0 - 3 + k;
                cc = (cc < 0) ? (-1 - cc) : ((cc > kW - 1) ? (2 * kW - 1 - cc) : cc);
                xv[k] = rowp[cc];
            }
        }

        unsigned int pk[4];
        #pragma unroll
        for (int u = 0; u < 4; ++u) {
            const float lo = h0[0] * xv[u + 1] + h0[1] * xv[u + 2] + h0[2] * xv[u + 3]
                           + h0[3] * xv[u + 4] + h0[4] * xv[u + 5];
            const float hi = h1[0] * xv[u + 0] + h1[1] * xv[u + 1] + h1[2] * xv[u + 2]
                           + h1[3] * xv[u + 3] + h1[4] * xv[u + 4] + h1[5] * xv[u + 5]
                           + h1[6] * xv[u + 6];
            __half2 p = __floats2half2_rn(lo, hi);
            pk[u] = __builtin_bit_cast(unsigned int, p);
        }
        *reinterpret_cast<uint4*>(&sLH[s][c0]) =
            make_uint4(pk[0], pk[1], pk[2], pk[3]);
    }
    __syncthreads();

    // ---------------- Phase 2: 2 output pixels per thread ----------------
    const int n = ch / kC;
    const int c = ch - n * kC;
    const size_t plane   = (size_t)kOH * kOW;      // 12544
    const size_t ostride = (size_t)kC * plane;     // orientation stride in output
    float* __restrict__ outp = out + ((size_t)n * 7 * kC + c) * plane;

    // Tasks: R_OUT rows x 56 pixel-pairs = 448.
    for (int task = tid; task < R_OUT * 56; task += 256) {
        const int ii = task / 56;                  // 0..R_OUT-1
        const int jp = task - ii * 56;             // pixel pair: j0=2jp, j1=2jp+1
        const int s1 = 2 * ii + 3;                 // LDS row of image row 2*(i0+ii)

        Acc A0, A1;
        acc_init(A0);
        acc_init(A1);

        #pragma unroll
        for (int k = 0; k < 8; ++k) {
            // Window cols 4jp..4jp+3 ({lo,hi} packed): one 16B LDS read.
            const uint4 w = *reinterpret_cast<const uint4*>(&sLH[s1 - 3 + k][4 * jp]);
            float lo00, hi00, lo01, hi01, lo10, hi10, lo11, hi11;
            unpack2(w.x, lo00, hi00);              // col 4jp   (pixel0 even col)
            unpack2(w.y, lo01, hi01);              // col 4jp+1 (pixel0 odd col)
            unpack2(w.z, lo10, hi10);              // col 4jp+2 (pixel1 even col)
            unpack2(w.w, lo11, hi11);              // col 4jp+3 (pixel1 odd col)
            acc_step(A0, k, lo00, hi00, lo01, hi01, h0, h1);
            acc_step(A1, k, lo10, hi10, lo11, hi11, h0, h1);
        }

        const float llp0 = fmaxf(fmaxf(A0.ll_a, A0.ll_b), fmaxf(A0.ll_c, A0.ll_d));
        const float llp1 = fmaxf(fmaxf(A1.ll_a, A1.ll_b), fmaxf(A1.ll_c, A1.ll_d));

        // q2c magnitudes: a=even/even, b=even/odd, c=odd/even, d=odd/odd
        const float m15_0  = magf((A0.lh_a - A0.lh_d) * kSqrtHalf, (A0.lh_b + A0.lh_c) * kSqrtHalf);
        const float m165_0 = magf((A0.lh_a + A0.lh_d) * kSqrtHalf, (A0.lh_b - A0.lh_c) * kSqrtHalf);
        const float m45_0  = magf((A0.hh_a - A0.hh_d) * kSqrtHalf, (A0.hh_b + A0.hh_c) * kSqrtHalf);
        const float m135_0 = magf((A0.hh_a + A0.hh_d) * kSqrtHalf, (A0.hh_b - A0.hh_c) * kSqrtHalf);
        const float m75_0  = magf((A0.hl_a - A0.hl_d) * kSqrtHalf, (A0.hl_b + A0.hl_c) * kSqrtHalf);
        const float m105_0 = magf((A0.hl_a + A0.hl_d) * kSqrtHalf, (A0.hl_b - A0.hl_c) * kSqrtHalf);

        const float m15_1  = magf((A1.lh_a - A1.lh_d) * kSqrtHalf, (A1.lh_b + A1.lh_c) * kSqrtHalf);
        const float m165_1 = magf((A1.lh_a + A1.lh_d) * kSqrtHalf, (A1.lh_b - A1.lh_c) * kSqrtHalf);
        const float m45_1  = magf((A1.hh_a - A1.hh_d) * kSqrtHalf, (A1.hh_b + A1.hh_c) * kSqrtHalf);
        const float m135_1 = magf((A1.hh_a + A1.hh_d) * kSqrtHalf, (A1.hh_b - A1.hh_c) * kSqrtHalf);
        const float m75_1  = magf((A1.hl_a - A1.hl_d) * kSqrtHalf, (A1.hl_b + A1.hl_c) * kSqrtHalf);
        const float m105_1 = magf((A1.hl_a + A1.hl_d) * kSqrtHalf, (A1.hl_b - A1.hl_c) * kSqrtHalf);

        // Nontemporal dwordx2 stores: output is write-once, keep it out of L2/L3.
        const size_t pix = (size_t)(i0 + ii) * kOW + 2 * jp;
        nt_store2(outp + pix,               llp0,   llp1);
        nt_store2(outp + ostride     + pix, m15_0,  m15_1);
        nt_store2(outp + 2 * ostride + pix, m45_0,  m45_1);
        nt_store2(outp + 3 * ostride + pix, m75_0,  m75_1);
        nt_store2(outp + 4 * ostride + pix, m105_0, m105_1);
        nt_store2(outp + 5 * ostride + pix, m135_0, m135_1);
        nt_store2(outp + 6 * ostride + pix, m165_0, m165_1);
    }
}

extern "C" void kernel_launch(void* const* d_in, const int* in_sizes, int n_in,
                              void* d_out, int out_size, void* d_ws, size_t ws_size,
                              hipStream_t stream) {
    const float* x = (const float*)d_in[0];
    float* out = (float*)d_out;
    scat_fused_kernel<<<kGrid, 256, 0, stream>>>(x, out);
}